// Round 9
// baseline (222.452 us; speedup 1.0000x reference)
//
#include <hip/hip_runtime.h>
#include <hip/hip_bf16.h>

// Problem dims (fixed by reference)
#define L_DIM 2048
#define B_DIM 8
#define D_DIM 1024
#define M_DIM (L_DIM * B_DIM)   // 16384 rows of x_norm
#define N_DIM (3 * D_DIM)       // 3072
#define K_DIM D_DIM             // 1024
#define BD (B_DIM * D_DIM)      // 8192 independent recurrence chains
#define NCHUNK 64
#define CLEN (L_DIM / NCHUNK)   // 32

typedef __attribute__((ext_vector_type(8))) __bf16 bf16x8;
typedef __attribute__((ext_vector_type(4))) __bf16 bf16x4;
typedef __attribute__((ext_vector_type(4))) float f32x4;

#define GLOAD_LDS16(g, l)                                        \
  __builtin_amdgcn_global_load_lds(                              \
      (const __attribute__((address_space(1))) void*)(g),        \
      (__attribute__((address_space(3))) void*)(l), 16, 0, 0)

__device__ __forceinline__ float sigmoidf_(float v) {
  return 1.0f / (1.0f + __expf(-v));
}

// ---------------------------------------------------------------------------
// Kernel 1: LayerNorm per (l,b) row of D=1024.
// ---------------------------------------------------------------------------
__global__ __launch_bounds__(256) void ln_kernel(
    const float* __restrict__ x, const float* __restrict__ gamma,
    const float* __restrict__ beta, __bf16* __restrict__ xn) {
  const int row = blockIdx.x;
  const int tid = threadIdx.x;
  const float4 v = ((const float4*)(x + (size_t)row * D_DIM))[tid];
  float s  = v.x + v.y + v.z + v.w;
  float ss = v.x * v.x + v.y * v.y + v.z * v.z + v.w * v.w;
  #pragma unroll
  for (int off = 32; off > 0; off >>= 1) {
    s  += __shfl_xor(s, off);
    ss += __shfl_xor(ss, off);
  }
  __shared__ float sb[8];
  const int wid = tid >> 6, lane = tid & 63;
  if (lane == 0) { sb[wid] = s; sb[4 + wid] = ss; }
  __syncthreads();
  const float tot  = sb[0] + sb[1] + sb[2] + sb[3];
  const float tot2 = sb[4] + sb[5] + sb[6] + sb[7];
  const float mu  = tot * (1.0f / D_DIM);
  const float var = tot2 * (1.0f / D_DIM) - mu * mu;
  const float rstd = rsqrtf(var + 1e-5f);
  const float4 g  = ((const float4*)gamma)[tid];
  const float4 bt = ((const float4*)beta)[tid];
  bf16x4 o;
  o[0] = (__bf16)((v.x - mu) * rstd * g.x + bt.x);
  o[1] = (__bf16)((v.y - mu) * rstd * g.y + bt.y);
  o[2] = (__bf16)((v.z - mu) * rstd * g.z + bt.z);
  o[3] = (__bf16)((v.w - mu) * rstd * g.w + bt.w);
  ((bf16x4*)(xn + (size_t)row * D_DIM))[tid] = o;
}

// ---------------------------------------------------------------------------
// Kernel 2: W fp32 -> bf16
// ---------------------------------------------------------------------------
__global__ __launch_bounds__(256) void wconv_kernel(
    const float* __restrict__ W, __bf16* __restrict__ Wb) {
  const size_t i = ((size_t)blockIdx.x * 256 + threadIdx.x) * 4;
  const float4 v = *(const float4*)(W + i);
  bf16x4 o;
  o[0] = (__bf16)v.x; o[1] = (__bf16)v.y; o[2] = (__bf16)v.z; o[3] = (__bf16)v.w;
  *(bf16x4*)(Wb + i) = o;
}

// ---------------------------------------------------------------------------
// Kernel 3: 256x256 GEMM, m201 8-phase template (T1+T2-equivalent+T3+T4+T5).
//
// 8 waves 2x4 (wm,wn), per-wave 128x64 = acc[8][4]; BK=64; LDS 128 KiB =
// 2 buf x [A 256x64 | B 256x64] bf16. 1 block/CU, VGPR ~217 (no bounds cap).
//
// 8 phases / 2 K-tiles (tE=2i buf0, tO=2i+1 buf1). Reads: B all-frags +
// A[mh0] at p1 (tE) / p5 (tO); A[mh1] at p3 / p7. Each phase stages exactly
// one half-tile (2 gload_lds w16/thread), rotation:
//   p1: tO.Ah1  p2: tE2.Bh0  p3: tE2.Bh1  p4: tE2.Ah0
//   p5: tE2.Ah1 p6: tO2.Bh0  p7: tO2.Bh1  p8: tO2.Ah0   (tE2=2i+2, tO2=2i+3)
// WAR: every stage slot is >=1 barrier after its region's last read (B last
// read p1/p5; Ah0 last read p3/p7 (wm0 mh1); Ah1 last read p3/p7 (wm1)).
// vmcnt(6) ONLY at p4/p8 (3 newest HT in flight): p4 proves tO complete
// (last HT staged p1 = 4th newest); p8 proves tE2 complete. Prologue: t0 x4
// + t1.{Bh0,Bh1,Ah0}; vmcnt(6). Tail i=7: p1 stage only; p4 vmcnt(0).
//
// Swizzle (r3-r8 proven, ~0 conflicts): [row][8 slots x 16B], global src
// slot = (c&7)^(row&7), LDS linear; frag read slot = (kk*4+fk)^(fr&7).
// ---------------------------------------------------------------------------
#define VMCNT(n) asm volatile("s_waitcnt vmcnt(" #n ")" ::: "memory")
#define BAR __builtin_amdgcn_s_barrier

__global__ __launch_bounds__(512) void gemm256_kernel(
    const __bf16* __restrict__ A,   // [M][K]
    const __bf16* __restrict__ Bm,  // [N][K]
    const float* __restrict__ bias,
    __bf16* __restrict__ U, __bf16* __restrict__ FG, __bf16* __restrict__ RG) {
  __shared__ __bf16 lds[65536];   // 128 KiB
  const int tid = threadIdx.x;
  const int lane = tid & 63;
  const int wid = tid >> 6;       // 0..7
  const int wm = wid >> 2;        // 0..1  row half (128 rows)
  const int wn = wid & 3;         // 0..3  col quarter (64 cols)

  // XCD-bijective swizzle: 768 blocks, 768 % 8 == 0. bn fastest.
  const int bid0 = blockIdx.x;
  const int bid = (bid0 & 7) * 96 + (bid0 >> 3);
  const int bm = bid / 12, bn = bid % 12;

  const int srow  = tid >> 3;                       // 0..63
  const int sslot = (tid & 7) ^ (srow & 7);         // swizzled 16B slot

  // Stage half h (rows h*128..+127) of K-tile t into buf t&1.
  auto stageA = [&](int t, int h) {
    const __bf16* gs = A + (size_t)(bm * 256 + h * 128 + srow) * K_DIM +
                       t * 64 + sslot * 8;
    __bf16* ld = lds + (t & 1) * 32768 + h * 8192 + tid * 8;
    GLOAD_LDS16(gs, ld);
    GLOAD_LDS16(gs + (size_t)64 * K_DIM, ld + 4096);
  };
  auto stageB = [&](int t, int h) {
    const __bf16* gs = Bm + (size_t)(bn * 256 + h * 128 + srow) * K_DIM +
                       t * 64 + sslot * 8;
    __bf16* ld = lds + (t & 1) * 32768 + 16384 + h * 8192 + tid * 8;
    GLOAD_LDS16(gs, ld);
    GLOAD_LDS16(gs + (size_t)64 * K_DIM, ld + 4096);
  };

  const int fr = lane & 15, fk = lane >> 4;
  auto rdA = [&](int buf, int m, int kk) {   // m 0..7
    const int row = wm * 128 + m * 16 + fr;
    return *(const bf16x8*)(lds + buf * 32768 + row * 64 +
                            (((kk * 4 + fk) ^ (fr & 7)) * 8));
  };
  auto rdB = [&](int buf, int n, int kk) {   // n 0..3
    const int row = wn * 64 + n * 16 + fr;
    return *(const bf16x8*)(lds + buf * 32768 + 16384 + row * 64 +
                            (((kk * 4 + fk) ^ (fr & 7)) * 8));
  };

  f32x4 acc[8][4] = {};
  bf16x8 a[4][2], b[4][2];

  auto cluster = [&](int mb, int nb) {   // 16 MFMA: 4m x 2n x 2kk
    __builtin_amdgcn_s_setprio(1);
    #pragma unroll
    for (int mm = 0; mm < 4; ++mm)
      #pragma unroll
      for (int nn = 0; nn < 2; ++nn)
        #pragma unroll
        for (int kk = 0; kk < 2; ++kk)
          acc[mb + mm][nb + nn] = __builtin_amdgcn_mfma_f32_16x16x32_bf16(
              a[mm][kk], b[nb + nn][kk], acc[mb + mm][nb + nn], 0, 0, 0);
    __builtin_amdgcn_s_setprio(0);
  };

  // Prologue: t0 fully + t1.{Bh0,Bh1,Ah0} (7 HT); vmcnt(6) -> t0 landed.
  stageA(0, 0); stageA(0, 1); stageB(0, 0); stageB(0, 1);
  stageB(1, 0); stageB(1, 1); stageA(1, 0);
  VMCNT(6);
  BAR();

  #pragma unroll 1
  for (int i = 0; i < 8; ++i) {
    const int tE = 2 * i, tO = 2 * i + 1;
    const bool full = (i < 7);
    // ---- p1: reads A[mh0]+B(all) of tE; stage tO.Ah1 ----
    #pragma unroll
    for (int m = 0; m < 4; ++m) { a[m][0] = rdA(0, m, 0); a[m][1] = rdA(0, m, 1); }
    #pragma unroll
    for (int n = 0; n < 4; ++n) { b[n][0] = rdB(0, n, 0); b[n][1] = rdB(0, n, 1); }
    stageA(tO, 1);
    BAR(); cluster(0, 0); BAR();
    // ---- p2 ----
    if (full) stageB(tE + 2, 0);
    BAR(); cluster(0, 2); BAR();
    // ---- p3: reads A[mh1] of tE ----
    #pragma unroll
    for (int m = 0; m < 4; ++m) { a[m][0] = rdA(0, m + 4, 0); a[m][1] = rdA(0, m + 4, 1); }
    if (full) stageB(tE + 2, 1);
    BAR(); cluster(4, 0); BAR();
    // ---- p4 ----
    if (full) stageA(tE + 2, 0);
    BAR(); cluster(4, 2);
    if (full) { VMCNT(6); } else { VMCNT(0); }   // tO complete
    BAR();
    // ---- p5: reads A[mh0]+B(all) of tO; stage tE2.Ah1 ----
    #pragma unroll
    for (int m = 0; m < 4; ++m) { a[m][0] = rdA(1, m, 0); a[m][1] = rdA(1, m, 1); }
    #pragma unroll
    for (int n = 0; n < 4; ++n) { b[n][0] = rdB(1, n, 0); b[n][1] = rdB(1, n, 1); }
    if (full) stageA(tE + 2, 1);
    BAR(); cluster(0, 0); BAR();
    // ---- p6 ----
    if (full) stageB(tO + 2, 0);
    BAR(); cluster(0, 2); BAR();
    // ---- p7: reads A[mh1] of tO ----
    #pragma unroll
    for (int m = 0; m < 4; ++m) { a[m][0] = rdA(1, m + 4, 0); a[m][1] = rdA(1, m + 4, 1); }
    if (full) stageB(tO + 2, 1);
    BAR(); cluster(4, 0); BAR();
    // ---- p8 ----
    if (full) stageA(tO + 2, 0);
    BAR(); cluster(4, 2);
    if (full) { VMCNT(6); }                      // tE2 complete
    BAR();
  }

  // Epilogue: acc -> LDS ([128 rows][264 cols] bf16, 2 half-phases by wm) ->
  // coalesced 16B stores. All staging drained (vmcnt(0) at i=7 p4).
  const int seg = bn >> 2;  // 0:u 1:f 2:r (256-wide tiles lie in one segment)
  __bf16* outb = (seg == 0) ? U : ((seg == 1) ? FG : RG);
  const int segcol0 = (bn & 3) * 256;

  float bv[4];
  #pragma unroll
  for (int n = 0; n < 4; ++n)
    bv[n] = bias[seg * 1024 + segcol0 + wn * 64 + n * 16 + fr];

  const int lrow = tid >> 5;        // 0..15 (readback)
  const int chunk = tid & 31;       // 16B chunk within 512B row
  #pragma unroll 1
  for (int h = 0; h < 2; ++h) {
    __syncthreads();
    if (wm == h) {
      #pragma unroll
      for (int m = 0; m < 8; ++m)
        #pragma unroll
        for (int n = 0; n < 4; ++n)
          #pragma unroll
          for (int j = 0; j < 4; ++j) {
            float v = acc[m][n][j] + bv[n];
            if (seg != 0) v = sigmoidf_(v);
            lds[(m * 16 + fk * 4 + j) * 264 + wn * 64 + n * 16 + fr] =
                (__bf16)v;
          }
    }
    __syncthreads();
    #pragma unroll
    for (int it = 0; it < 8; ++it) {
      const int r = it * 16 + lrow;
      const bf16x8 val = *(const bf16x8*)(lds + r * 264 + chunk * 8);
      const size_t grow = (size_t)(bm * 256 + h * 128 + r);
      *(bf16x8*)(outb + grow * D_DIM + segcol0 + chunk * 8) = val;
    }
  }
}

// ---------------------------------------------------------------------------
// Scan pass A: per (chunk, bd) affine composition over CLEN steps.
// ---------------------------------------------------------------------------
__global__ __launch_bounds__(256) void scanA_kernel(
    const __bf16* __restrict__ fg, const __bf16* __restrict__ u,
    float* __restrict__ av) {
  const int ci = blockIdx.x;
  const int bd = blockIdx.y * 256 + threadIdx.x;
  float a = 1.0f, v = 0.0f;
  const size_t base = (size_t)ci * CLEN * BD + bd;
  #pragma unroll 8
  for (int i = 0; i < CLEN; ++i) {
    const size_t idx = base + (size_t)i * BD;
    const float f = (float)fg[idx];
    const float uu = (float)u[idx];
    a *= f;
    v = f * v + (1.0f - f) * uu;
  }
  av[(size_t)ci * BD + bd] = a;
  av[(size_t)NCHUNK * BD + (size_t)ci * BD + bd] = v;
}

// ---------------------------------------------------------------------------
// Scan pass B: sequential combine across chunks; writes last_c.
// ---------------------------------------------------------------------------
__global__ __launch_bounds__(256) void scanB_kernel(
    const float* __restrict__ av, const float* __restrict__ c0,
    float* __restrict__ carries, float* __restrict__ out1) {
  const int bd = blockIdx.x * 256 + threadIdx.x;
  float c = c0[bd];
  #pragma unroll 8
  for (int ci = 0; ci < NCHUNK; ++ci) {
    carries[(size_t)ci * BD + bd] = c;
    c = av[(size_t)ci * BD + bd] * c + av[(size_t)NCHUNK * BD + (size_t)ci * BD + bd];
  }
  out1[bd] = c;
}

// ---------------------------------------------------------------------------
// Scan pass C: re-run recurrence within chunk, fuse hs + residual.
// ---------------------------------------------------------------------------
__global__ __launch_bounds__(256) void scanC_kernel(
    const __bf16* __restrict__ fg, const __bf16* __restrict__ u,
    const __bf16* __restrict__ rg, const __bf16* __restrict__ xn,
    const float* __restrict__ x, const float* __restrict__ carries,
    float* __restrict__ out0) {
  const int ci = blockIdx.x;
  const int bd = blockIdx.y * 256 + threadIdx.x;
  float c = carries[(size_t)ci * BD + bd];
  const size_t base = (size_t)ci * CLEN * BD + bd;
  #pragma unroll 4
  for (int i = 0; i < CLEN; ++i) {
    const size_t idx = base + (size_t)i * BD;
    const float f = (float)fg[idx];
    const float uu = (float)u[idx];
    c = f * c + (1.0f - f) * uu;
    const float r = (float)rg[idx];
    const float xnv = (float)xn[idx];
    const float hs = r * tanhf(c) + (1.0f - r) * xnv;
    out0[idx] = x[idx] + hs;
  }
}

// ---------------------------------------------------------------------------
extern "C" void kernel_launch(void* const* d_in, const int* in_sizes, int n_in,
                              void* d_out, int out_size, void* d_ws,
                              size_t ws_size, hipStream_t stream) {
  const float* x     = (const float*)d_in[0];
  const float* c0    = (const float*)d_in[1];
  const float* W     = (const float*)d_in[2];
  const float* bias  = (const float*)d_in[3];
  const float* gamma = (const float*)d_in[4];
  const float* beta  = (const float*)d_in[5];

  float* out0 = (float*)d_out;                 // [L,B,D]
  float* out1 = out0 + (size_t)M_DIM * D_DIM;  // [B,D]

  char* ws = (char*)d_ws;
  __bf16* xn = (__bf16*)(ws + 0);              // 32 MB
  __bf16* Wb = (__bf16*)(ws + 33554432);       //  6 MB
  __bf16* U  = (__bf16*)(ws + 39845888);       // 32 MB
  __bf16* FG = (__bf16*)(ws + 73400320);       // 32 MB
  __bf16* RG = (__bf16*)(ws + 106954752);      // 32 MB
  float* av      = (float*)(ws + 140509184);   //  4 MB
  float* carries = (float*)(ws + 144703488);   //  2 MB

  ln_kernel<<<M_DIM, 256, 0, stream>>>(x, gamma, beta, xn);
  wconv_kernel<<<(N_DIM * K_DIM / 4) / 256, 256, 0, stream>>>(W, Wb);
  gemm256_kernel<<<(M_DIM / 256) * (N_DIM / 256), 512, 0, stream>>>(
      xn, Wb, bias, U, FG, RG);
  scanA_kernel<<<dim3(NCHUNK, BD / 256), 256, 0, stream>>>(FG, U, av);
  scanB_kernel<<<BD / 256, 256, 0, stream>>>(av, c0, carries, out1);
  scanC_kernel<<<dim3(NCHUNK, BD / 256), 256, 0, stream>>>(
      FG, U, RG, xn, x, carries, out0);
}

// Round 10
// 214.194 us; speedup vs baseline: 1.0386x; 1.0386x over previous
//
#include <hip/hip_runtime.h>
#include <hip/hip_bf16.h>

// Problem dims (fixed by reference)
#define L_DIM 2048
#define B_DIM 8
#define D_DIM 1024
#define M_DIM (L_DIM * B_DIM)   // 16384 rows of x_norm
#define N_DIM (3 * D_DIM)       // 3072
#define K_DIM D_DIM             // 1024
#define BD (B_DIM * D_DIM)      // 8192 independent recurrence chains
#define NCHUNK 64
#define CLEN (L_DIM / NCHUNK)   // 32

typedef __attribute__((ext_vector_type(8))) __bf16 bf16x8;
typedef __attribute__((ext_vector_type(4))) __bf16 bf16x4;
typedef __attribute__((ext_vector_type(4))) float f32x4;

#define GLOAD_LDS16(g, l)                                        \
  __builtin_amdgcn_global_load_lds(                              \
      (const __attribute__((address_space(1))) void*)(g),        \
      (__attribute__((address_space(3))) void*)(l), 16, 0, 0)

__device__ __forceinline__ float sigmoidf_(float v) {
  return 1.0f / (1.0f + __expf(-v));
}

// ---------------------------------------------------------------------------
// Kernel 1: LayerNorm per (l,b) row of D=1024. Also emits mu/rstd per row
// (64 KB arrays) so scanC can recompute xn from x instead of re-reading it.
// ---------------------------------------------------------------------------
__global__ __launch_bounds__(256) void ln_kernel(
    const float* __restrict__ x, const float* __restrict__ gamma,
    const float* __restrict__ beta, __bf16* __restrict__ xn,
    float* __restrict__ muA, float* __restrict__ rsA) {
  const int row = blockIdx.x;
  const int tid = threadIdx.x;
  const float4 v = ((const float4*)(x + (size_t)row * D_DIM))[tid];
  float s  = v.x + v.y + v.z + v.w;
  float ss = v.x * v.x + v.y * v.y + v.z * v.z + v.w * v.w;
  #pragma unroll
  for (int off = 32; off > 0; off >>= 1) {
    s  += __shfl_xor(s, off);
    ss += __shfl_xor(ss, off);
  }
  __shared__ float sb[8];
  const int wid = tid >> 6, lane = tid & 63;
  if (lane == 0) { sb[wid] = s; sb[4 + wid] = ss; }
  __syncthreads();
  const float tot  = sb[0] + sb[1] + sb[2] + sb[3];
  const float tot2 = sb[4] + sb[5] + sb[6] + sb[7];
  const float mu  = tot * (1.0f / D_DIM);
  const float var = tot2 * (1.0f / D_DIM) - mu * mu;
  const float rstd = rsqrtf(var + 1e-5f);
  if (tid == 0) { muA[row] = mu; rsA[row] = rstd; }
  const float4 g  = ((const float4*)gamma)[tid];
  const float4 bt = ((const float4*)beta)[tid];
  bf16x4 o;
  o[0] = (__bf16)((v.x - mu) * rstd * g.x + bt.x);
  o[1] = (__bf16)((v.y - mu) * rstd * g.y + bt.y);
  o[2] = (__bf16)((v.z - mu) * rstd * g.z + bt.z);
  o[3] = (__bf16)((v.w - mu) * rstd * g.w + bt.w);
  ((bf16x4*)(xn + (size_t)row * D_DIM))[tid] = o;
}

// ---------------------------------------------------------------------------
// Kernel 2: W fp32 -> bf16
// ---------------------------------------------------------------------------
__global__ __launch_bounds__(256) void wconv_kernel(
    const float* __restrict__ W, __bf16* __restrict__ Wb) {
  const size_t i = ((size_t)blockIdx.x * 256 + threadIdx.x) * 4;
  const float4 v = *(const float4*)(W + i);
  bf16x4 o;
  o[0] = (__bf16)v.x; o[1] = (__bf16)v.y; o[2] = (__bf16)v.z; o[3] = (__bf16)v.w;
  *(bf16x4*)(Wb + i) = o;
}

// ---------------------------------------------------------------------------
// Kernel 3: 128x128 GEMM, BK=64, single-buffer m97 structure (r8, measured
// best: 138 us, K-loop ~ m97 reference rate). Two __syncthreads per K-tile;
// ~3 blocks/CU provide the cross-block overlap that hides the drain (m114).
// Swizzle (r3-r8 proven, ~0 conflicts): [row][8 slots x 16B], global src
// slot = (c&7)^(row&7), LDS linear; frag read slot = (kk*4+fk)^(fr&7).
// ---------------------------------------------------------------------------
__global__ __launch_bounds__(256) void gemm_kernel(
    const __bf16* __restrict__ A,   // [M][K]
    const __bf16* __restrict__ Bm,  // [N][K]
    const float* __restrict__ bias,
    __bf16* __restrict__ U, __bf16* __restrict__ FG, __bf16* __restrict__ RG) {
  __shared__ __bf16 lds[17408];   // 34.8 KB (tiles use 32 KB; epilogue 34.8)
  const int tid = threadIdx.x;
  const int lane = tid & 63;
  const int wid = tid >> 6;       // 0..3
  const int wm = wid >> 1;        // 0..1  row half (64 rows)
  const int wc = wid & 1;         // 0..1  col half (64 cols)

  // XCD-bijective swizzle: 3072 blocks, 3072 % 8 == 0. bn fastest -> the 24
  // blocks sharing an A panel are consecutive on one XCD (A panel L2-hot).
  const int bid0 = blockIdx.x;
  const int bid = (bid0 & 7) * 384 + (bid0 >> 3);
  const int bm = bid / 24, bn = bid % 24;

  const int srow  = tid >> 3;                       // 0..31
  const int sslot = (tid & 7) ^ (srow & 7);         // swizzled 16B slot
  const __bf16* aSrc = A + (size_t)(bm * 128 + srow) * K_DIM + sslot * 8;
  const __bf16* bSrc = Bm + (size_t)(bn * 128 + srow) * K_DIM + sslot * 8;

  const int fr = lane & 15, fk = lane >> 4;
  const int swzbase = fk ^ (fr & 7);  // slot for kk=0; kk=1 adds XOR 4
  auto rdA = [&](int kk, int m) {
    return *(const bf16x8*)(lds + (wm * 64 + m * 16 + fr) * 64 +
                            ((kk * 4) ^ swzbase) * 8);
  };
  auto rdB = [&](int kk, int n) {
    return *(const bf16x8*)(lds + 8192 + (wc * 64 + n * 16 + fr) * 64 +
                            ((kk * 4) ^ swzbase) * 8);
  };

  f32x4 acc[4][4] = {};

  #pragma unroll 1
  for (int kt = 0; kt < 16; ++kt) {
    __syncthreads();                 // WAR: previous tile's reads complete
    #pragma unroll
    for (int i = 0; i < 4; ++i) {
      GLOAD_LDS16(aSrc + (size_t)(32 * i) * K_DIM + kt * 64,
                  lds + (tid + 256 * i) * 8);
      GLOAD_LDS16(bSrc + (size_t)(32 * i) * K_DIM + kt * 64,
                  lds + 8192 + (tid + 256 * i) * 8);
    }
    __syncthreads();                 // drains vmcnt(0): tile visible

    #pragma unroll
    for (int kk = 0; kk < 2; ++kk) {
      bf16x8 a[4], b[4];
      #pragma unroll
      for (int m = 0; m < 4; ++m) a[m] = rdA(kk, m);
      #pragma unroll
      for (int n = 0; n < 4; ++n) b[n] = rdB(kk, n);
      __builtin_amdgcn_s_setprio(1);
      #pragma unroll
      for (int m = 0; m < 4; ++m)
        #pragma unroll
        for (int n = 0; n < 4; ++n)
          acc[m][n] = __builtin_amdgcn_mfma_f32_16x16x32_bf16(
              a[m], b[n], acc[m][n], 0, 0, 0);
      __builtin_amdgcn_s_setprio(0);
    }
  }

  // Epilogue: acc -> LDS (bf16, [128 rows][136 cols]) -> coalesced stores.
  const int seg = bn >> 3;  // 0:u 1:f 2:r (128-wide tiles lie in one segment)
  __bf16* outb = (seg == 0) ? U : ((seg == 1) ? FG : RG);
  const int segcol0 = (bn & 7) * 128;

  float bv[4];
  #pragma unroll
  for (int n = 0; n < 4; ++n)
    bv[n] = bias[seg * 1024 + segcol0 + wc * 64 + n * 16 + fr];

  __syncthreads();   // tile reads done before overwriting LDS with output
  #pragma unroll
  for (int m = 0; m < 4; ++m)
    #pragma unroll
    for (int n = 0; n < 4; ++n)
      #pragma unroll
      for (int j = 0; j < 4; ++j) {
        float v = acc[m][n][j] + bv[n];
        if (seg != 0) v = sigmoidf_(v);
        lds[(wm * 64 + m * 16 + fk * 4 + j) * 136 + wc * 64 + n * 16 + fr] =
            (__bf16)v;
      }
  __syncthreads();
  const int lrow = tid >> 4;        // 0..15 (readback)
  const int chunk = tid & 15;       // 16B chunk within 256B row
  #pragma unroll
  for (int it = 0; it < 8; ++it) {
    const int r = it * 16 + lrow;
    const bf16x8 val = *(const bf16x8*)(lds + r * 136 + chunk * 8);
    const size_t grow = (size_t)(bm * 128 + r);
    *(bf16x8*)(outb + grow * D_DIM + segcol0 + chunk * 8) = val;
  }
}

// ---------------------------------------------------------------------------
// Scan pass A: per (chunk, 8 chains) affine composition over CLEN steps.
// Vectorized: bf16x8 gate loads (16 B/lane), 8 chains per thread.
// ---------------------------------------------------------------------------
__global__ __launch_bounds__(256) void scanA_kernel(
    const __bf16* __restrict__ fg, const __bf16* __restrict__ u,
    float* __restrict__ av) {
  const int ci = blockIdx.x;
  const int t8 = blockIdx.y * 256 + threadIdx.x;   // 0..1023
  const int bd0 = t8 * 8;
  float a[8], v[8];
  #pragma unroll
  for (int j = 0; j < 8; ++j) { a[j] = 1.0f; v[j] = 0.0f; }
  const size_t base = (size_t)ci * CLEN * BD + bd0;
  #pragma unroll 4
  for (int i = 0; i < CLEN; ++i) {
    const size_t idx = base + (size_t)i * BD;
    const bf16x8 fv = *(const bf16x8*)(fg + idx);
    const bf16x8 uv = *(const bf16x8*)(u + idx);
    #pragma unroll
    for (int j = 0; j < 8; ++j) {
      const float f = (float)fv[j];
      a[j] *= f;
      v[j] = f * v[j] + (1.0f - f) * (float)uv[j];
    }
  }
  float4* avA = (float4*)(av + (size_t)ci * BD + bd0);
  float4* avV = (float4*)(av + (size_t)NCHUNK * BD + (size_t)ci * BD + bd0);
  avA[0] = make_float4(a[0], a[1], a[2], a[3]);
  avA[1] = make_float4(a[4], a[5], a[6], a[7]);
  avV[0] = make_float4(v[0], v[1], v[2], v[3]);
  avV[1] = make_float4(v[4], v[5], v[6], v[7]);
}

// ---------------------------------------------------------------------------
// Scan pass B: sequential combine across chunks; writes last_c.
// ---------------------------------------------------------------------------
__global__ __launch_bounds__(256) void scanB_kernel(
    const float* __restrict__ av, const float* __restrict__ c0,
    float* __restrict__ carries, float* __restrict__ out1) {
  const int bd = blockIdx.x * 256 + threadIdx.x;
  float c = c0[bd];
  #pragma unroll 8
  for (int ci = 0; ci < NCHUNK; ++ci) {
    carries[(size_t)ci * BD + bd] = c;
    c = av[(size_t)ci * BD + bd] * c + av[(size_t)NCHUNK * BD + (size_t)ci * BD + bd];
  }
  out1[bd] = c;
}

// ---------------------------------------------------------------------------
// Scan pass C: re-run recurrence within chunk from the carry; recompute
// xn from x + (mu,rstd,gamma,beta) — drops the 32 MB xn read; fuse
// hs = r*tanh(c) + (1-r)*xn and residual. Vectorized 8 chains/thread.
// ---------------------------------------------------------------------------
__global__ __launch_bounds__(256) void scanC_kernel(
    const __bf16* __restrict__ fg, const __bf16* __restrict__ u,
    const __bf16* __restrict__ rg, const float* __restrict__ x,
    const float* __restrict__ muA, const float* __restrict__ rsA,
    const float* __restrict__ gamma, const float* __restrict__ beta,
    const float* __restrict__ carries, float* __restrict__ out0) {
  const int ci = blockIdx.x;
  const int t8 = blockIdx.y * 256 + threadIdx.x;   // 0..1023
  const int bd0 = t8 * 8;
  const int b = bd0 >> 10;          // batch index
  const int d0 = bd0 & 1023;        // first d of the 8

  float g[8], be[8], c[8];
  #pragma unroll
  for (int j = 0; j < 8; ++j) { g[j] = gamma[d0 + j]; be[j] = beta[d0 + j]; }
  {
    const float4* cp = (const float4*)(carries + (size_t)ci * BD + bd0);
    const float4 c0v = cp[0], c1v = cp[1];
    c[0] = c0v.x; c[1] = c0v.y; c[2] = c0v.z; c[3] = c0v.w;
    c[4] = c1v.x; c[5] = c1v.y; c[6] = c1v.z; c[7] = c1v.w;
  }

  const size_t base = (size_t)ci * CLEN * BD + bd0;
  #pragma unroll 2
  for (int i = 0; i < CLEN; ++i) {
    const size_t idx = base + (size_t)i * BD;
    const int row = (ci * CLEN + i) * B_DIM + b;
    const float mu = muA[row], rs = rsA[row];
    const bf16x8 fv = *(const bf16x8*)(fg + idx);
    const bf16x8 uv = *(const bf16x8*)(u + idx);
    const bf16x8 rv = *(const bf16x8*)(rg + idx);
    const float4* xp = (const float4*)(x + idx);
    const float4 x0 = xp[0], x1 = xp[1];
    const float xs[8] = {x0.x, x0.y, x0.z, x0.w, x1.x, x1.y, x1.z, x1.w};
    float os[8];
    #pragma unroll
    for (int j = 0; j < 8; ++j) {
      const float f = (float)fv[j];
      c[j] = f * c[j] + (1.0f - f) * (float)uv[j];
      const float r = (float)rv[j];
      const float xn = (xs[j] - mu) * rs * g[j] + be[j];
      const float hs = r * tanhf(c[j]) + (1.0f - r) * xn;
      os[j] = xs[j] + hs;
    }
    float4* op = (float4*)(out0 + idx);
    op[0] = make_float4(os[0], os[1], os[2], os[3]);
    op[1] = make_float4(os[4], os[5], os[6], os[7]);
  }
}

// ---------------------------------------------------------------------------
extern "C" void kernel_launch(void* const* d_in, const int* in_sizes, int n_in,
                              void* d_out, int out_size, void* d_ws,
                              size_t ws_size, hipStream_t stream) {
  const float* x     = (const float*)d_in[0];
  const float* c0    = (const float*)d_in[1];
  const float* W     = (const float*)d_in[2];
  const float* bias  = (const float*)d_in[3];
  const float* gamma = (const float*)d_in[4];
  const float* beta  = (const float*)d_in[5];

  float* out0 = (float*)d_out;                 // [L,B,D]
  float* out1 = out0 + (size_t)M_DIM * D_DIM;  // [B,D]

  char* ws = (char*)d_ws;
  __bf16* xn = (__bf16*)(ws + 0);              // 32 MB
  __bf16* Wb = (__bf16*)(ws + 33554432);       //  6 MB
  __bf16* U  = (__bf16*)(ws + 39845888);       // 32 MB
  __bf16* FG = (__bf16*)(ws + 73400320);       // 32 MB
  __bf16* RG = (__bf16*)(ws + 106954752);      // 32 MB
  float* av      = (float*)(ws + 140509184);   //  4 MB
  float* carries = (float*)(ws + 144703488);   //  2 MB
  float* muA     = (float*)(ws + 146800640);   // 64 KB
  float* rsA     = (float*)(ws + 146866176);   // 64 KB

  ln_kernel<<<M_DIM, 256, 0, stream>>>(x, gamma, beta, xn, muA, rsA);
  wconv_kernel<<<(N_DIM * K_DIM / 4) / 256, 256, 0, stream>>>(W, Wb);
  gemm_kernel<<<(M_DIM / 128) * (N_DIM / 128), 256, 0, stream>>>(
      xn, Wb, bias, U, FG, RG);
  scanA_kernel<<<dim3(NCHUNK, BD / 8 / 256), 256, 0, stream>>>(FG, U, av);
  scanB_kernel<<<BD / 256, 256, 0, stream>>>(av, c0, carries, out1);
  scanC_kernel<<<dim3(NCHUNK, BD / 8 / 256), 256, 0, stream>>>(
      FG, U, RG, x, muA, rsA, gamma, beta, carries, out0);
}